// Round 9
// baseline (374.408 us; speedup 1.0000x reference)
//
#include <hip/hip_runtime.h>
#include <cstdint>
#include <cstddef>
#include <cmath>

// ClipLoss fused: loss = mean_i( 0.5*(lse_row_i + lse_col_i) - diag_i )
// logits = SCALE * img @ txt^T. Stats in exp2 domain: fp8 img copy is
// pre-scaled by CF = SCALE*log2(e); lse_nat = ln2 * (m + log2(s)).
//
// A'/B' stored as e4m3 pre-swizzled [g][row][32 fp8] (g = 32-elem
// k-granule, 16 total). 16x16x128 f8f6f4 MFMA, unit E8M0 scales.
//
// History: R9 LDS dbuf (occupancy halved). R11 256x128 tile (VGPR-bound).
// R12 WIN: direct global->VGPR K-loop, no staging/barriers: gemm 196us.
// R13/R15 FAILED with IDENTICAL scratch signature (WRITE_SIZE 69k->491k):
// both used 8-wide register aggregates (union / int8v array) -> 8-aligned
// VGPR tuple allocation fails under the 64-VGPR cap -> wholesale spill.
// 4-wide int4v tuples (R12/R14) pack fine. int8v loads are BANNED.
// R14 WIN: R12 K-loop + float2-packed stats: total 284us (gemm 203).
//
// R16 (this round), de-confounded probes on the R14 base:
//  (1) setprio(1) around the mi-MFMA cluster ONLY (loads stay int4v).
//      setprio was present in both failures but never tested alone; our
//      regime (barrier-free, phase-drifted waves) is the one where it
//      measured +4-7%. If WRITE_SIZE blows up again, setprio is convicted.
//  (2) d_out zeroing folded into cvt_diag (drops the memset dispatch;
//      stream-ordered before reduce).

#define N_ROWS 16384
#define DIM    512
#define NB     128
#define SCALE  14.285714285714286f
#define CF     20.609929155556625f   // SCALE * log2(e)
#define LN2F   0.6931471805599453f
#define SP     36                    // part[] row stride in floats (144 B)

typedef __attribute__((ext_vector_type(8))) int   int8v;
typedef __attribute__((ext_vector_type(4))) int   int4v;
typedef __attribute__((ext_vector_type(4))) float floatx4;

#if __has_builtin(__builtin_amdgcn_exp2f)
#define EXP2(x) __builtin_amdgcn_exp2f(x)
#else
#define EXP2(x) exp2f(x)
#endif

// ---------------------------------------------------------------- helpers ---
__device__ __forceinline__ void lse_merge2(float& m, float& s, float om, float os) {
    float nm = fmaxf(m, om);
    s = s * EXP2(m - nm) + os * EXP2(om - nm);
    m = nm;
}

// pack 4 floats -> 4 e4m3 bytes in one i32 (RNE, OCP on gfx950)
__device__ __forceinline__ int pk_fp8x4(float a, float b, float c, float d) {
    int u = __builtin_amdgcn_cvt_pk_fp8_f32(a, b, 0, false);
    u = __builtin_amdgcn_cvt_pk_fp8_f32(c, d, u, true);
    return u;
}

__device__ __forceinline__ int8v frag8(int4v lo, int4v hi) {
    return (int8v){lo[0], lo[1], lo[2], lo[3], hi[0], hi[1], hi[2], hi[3]};
}

// --------------------------------------------- cvt + swizzle + diag ---------
// Block = 256 threads = 16 rows x 16 granules. Thread (rl, g16) converts
// img/txt[row][g16*32 .. +31] to fp8 (img scaled by CF) and writes the
// 32-B granule to A'/B' at ((g16*N + row)*32); also partial diag dot.
// R16: block 0 thread 0 zeroes *out (stream-ordered before reduce).
__global__ void cvt_diag_kernel(const float* __restrict__ a, const float* __restrict__ b,
                                unsigned char* __restrict__ A8, unsigned char* __restrict__ B8,
                                float* __restrict__ diag, float* __restrict__ out) {
    const int t  = threadIdx.x;
    if (blockIdx.x == 0 && t == 0) *out = 0.f;
    const int rl = t & 15, g16 = t >> 4;
    const int row = blockIdx.x * 16 + rl;
    const float4* ai = (const float4*)(a + (size_t)row * DIM + g16 * 32);
    const float4* bi = (const float4*)(b + (size_t)row * DIM + g16 * 32);
    float dot = 0.f;
    int wa[8], wb[8];
#pragma unroll
    for (int j = 0; j < 4; ++j) {
        float4 x0 = ai[2 * j], x1 = ai[2 * j + 1];
        float4 y0 = bi[2 * j], y1 = bi[2 * j + 1];
        dot += x0.x * y0.x + x0.y * y0.y + x0.z * y0.z + x0.w * y0.w
             + x1.x * y1.x + x1.y * y1.y + x1.z * y1.z + x1.w * y1.w;
        wa[2 * j]     = pk_fp8x4(CF * x0.x, CF * x0.y, CF * x0.z, CF * x0.w);
        wa[2 * j + 1] = pk_fp8x4(CF * x1.x, CF * x1.y, CF * x1.z, CF * x1.w);
        wb[2 * j]     = pk_fp8x4(y0.x, y0.y, y0.z, y0.w);
        wb[2 * j + 1] = pk_fp8x4(y1.x, y1.y, y1.z, y1.w);
    }
    const size_t o = ((size_t)g16 * N_ROWS + row) * 32;
    *(int4v*)(A8 + o)      = (int4v){wa[0], wa[1], wa[2], wa[3]};
    *(int4v*)(A8 + o + 16) = (int4v){wa[4], wa[5], wa[6], wa[7]};
    *(int4v*)(B8 + o)      = (int4v){wb[0], wb[1], wb[2], wb[3]};
    *(int4v*)(B8 + o + 16) = (int4v){wb[4], wb[5], wb[6], wb[7]};

    __shared__ float pd[16][17];
    pd[rl][g16] = dot;
    __syncthreads();
    if (t < 16) {
        float s = 0.f;
#pragma unroll
        for (int j = 0; j < 16; ++j) s += pd[t][j];
        diag[blockIdx.x * 16 + t] = SCALE * s;
    }
}

// --------------------------------------------------- fused GEMM + LSE -------
__global__ __launch_bounds__(256, 4)
void gemm_lse_kernel(const unsigned char* __restrict__ A8,
                     const unsigned char* __restrict__ B8,
                     float2* __restrict__ row_ms, float2* __restrict__ col_ms) {
    __shared__ __align__(16) float part[NB * SP];   // 18432 B, epilogue only

    const int t = threadIdx.x;
    const int bid = blockIdx.x;

    // XCD-aware swizzle: each XCD owns a 16-row A band (L2-resident), sweeps bc
    const int xcd   = bid & 7;
    const int local = bid >> 3;
    const int br    = xcd * 16 + (local & 15);
    const int bc    = local >> 4;

    const int lane = t & 63;
    const int w    = t >> 6;
    const int quad = lane >> 4;
    const int l15  = lane & 15;
    const int wrow = w >> 1;
    const int wcol = w & 1;

    floatx4 acc[4][4];
#pragma unroll
    for (int i = 0; i < 4; ++i)
#pragma unroll
        for (int j = 0; j < 4; ++j)
            acc[i][j] = (floatx4){0.f, 0.f, 0.f, 0.f};

    // per-lane byte offsets; granule index advances by 4 per kb step.
    // fragment (mi): 16 B at offA + mi*512 (+16 for hi half) -- 16-lane
    // groups read 512-B contiguous segments of the pre-swizzled layout.
    unsigned int offA = ((unsigned)quad * N_ROWS
                         + (unsigned)(br * 128 + wrow * 64 + l15)) * 32u;
    unsigned int offB = ((unsigned)quad * N_ROWS
                         + (unsigned)(bc * 128 + wcol * 64 + l15)) * 32u;
    const unsigned int kstep = 4u * N_ROWS * 32u;

#pragma unroll
    for (int kb = 0; kb < 4; ++kb) {
        int4v alo[4], ahi[4];
#pragma unroll
        for (int mi = 0; mi < 4; ++mi) {
            alo[mi] = *(const int4v*)(A8 + offA + mi * 512);
            ahi[mi] = *(const int4v*)(A8 + offA + mi * 512 + 16);
        }
#pragma unroll
        for (int ni = 0; ni < 4; ++ni) {
            int4v bl = *(const int4v*)(B8 + offB + ni * 512);
            int4v bh = *(const int4v*)(B8 + offB + ni * 512 + 16);
            int8v bv = frag8(bl, bh);
            __builtin_amdgcn_s_setprio(1);
#pragma unroll
            for (int mi = 0; mi < 4; ++mi)
                acc[mi][ni] = __builtin_amdgcn_mfma_scale_f32_16x16x128_f8f6f4(
                    frag8(alo[mi], ahi[mi]), bv, acc[mi][ni], 0, 0, 0, 127, 0, 127);
            __builtin_amdgcn_s_setprio(0);
        }
        offA += kstep;
        offB += kstep;
    }

    // ---- epilogue. C/D layout (16x16): col = lane&15, row = quad*4 + reg. ----
    // lane holds rows lrow = wrow*64+mi*16+quad*4+r, cols wcol*64+ni*16+l15.

    // phase A1: row partial max (over ni) -> part[lrow][wcol*16+l15]
#pragma unroll
    for (int mi = 0; mi < 4; ++mi)
#pragma unroll
        for (int r = 0; r < 4; ++r) {
            float pm = fmaxf(fmaxf(acc[mi][0][r], acc[mi][1][r]),
                             fmaxf(acc[mi][2][r], acc[mi][3][r]));
            int lrow = wrow * 64 + mi * 16 + quad * 4 + r;
            part[lrow * SP + wcol * 16 + l15] = pm;
        }

    // phase A2: col stats (shfl over quads) -> part[cl][32..35]
#pragma unroll
    for (int ni = 0; ni < 4; ++ni) {
        float m = acc[0][ni][0];
#pragma unroll
        for (int mi = 0; mi < 4; ++mi)
#pragma unroll
            for (int r = 0; r < 4; ++r)
                m = fmaxf(m, acc[mi][ni][r]);
        m = fmaxf(m, __shfl_xor(m, 16));
        m = fmaxf(m, __shfl_xor(m, 32));
        float s = 0.f;
#pragma unroll
        for (int mi = 0; mi < 4; ++mi)
#pragma unroll
            for (int r = 0; r < 4; ++r)
                s += EXP2(acc[mi][ni][r] - m);
        s += __shfl_xor(s, 16);
        s += __shfl_xor(s, 32);
        if (quad == 0) {
            int cl = wcol * 64 + ni * 16 + l15;
            part[cl * SP + 32 + wrow] = m;   // 32,33
            part[cl * SP + 34 + wrow] = s;   // 34,35
        }
    }
    __syncthreads();

    if (t < 128) {
        // finish cols: merge wrow halves, store packed (m,s)
        float m = part[t * SP + 32], s = part[t * SP + 34];
        lse_merge2(m, s, part[t * SP + 33], part[t * SP + 35]);
        col_ms[(size_t)br * N_ROWS + bc * 128 + t] = float2{m, s};
        // row max over 32 partials (8 x float4, stride 144 B)
        const float4* p4 = (const float4*)&part[t * SP];
        float4 v = p4[0];
#pragma unroll
        for (int j = 1; j < 8; ++j) {
            float4 u = p4[j];
            v.x = fmaxf(v.x, u.x); v.y = fmaxf(v.y, u.y);
            v.z = fmaxf(v.z, u.z); v.w = fmaxf(v.w, u.w);
        }
        part[t * SP + 32] = fmaxf(fmaxf(v.x, v.y), fmaxf(v.z, v.w));
    }
    __syncthreads();

    // phase B: row partial sums with broadcast max
#pragma unroll
    for (int mi = 0; mi < 4; ++mi)
#pragma unroll
        for (int r = 0; r < 4; ++r) {
            int lrow = wrow * 64 + mi * 16 + quad * 4 + r;
            float m = part[lrow * SP + 32];
            float s = EXP2(acc[mi][0][r] - m) + EXP2(acc[mi][1][r] - m)
                    + EXP2(acc[mi][2][r] - m) + EXP2(acc[mi][3][r] - m);
            part[lrow * SP + wcol * 16 + l15] = s;
        }
    __syncthreads();

    if (t < 128) {
        const float4* p4 = (const float4*)&part[t * SP];
        float4 v = p4[0];
#pragma unroll
        for (int j = 1; j < 8; ++j) {
            float4 u = p4[j];
            v.x += u.x; v.y += u.y; v.z += u.z; v.w += u.w;
        }
        float s = (v.x + v.y) + (v.z + v.w);
        float m = part[t * SP + 32];
        row_ms[(size_t)bc * N_ROWS + br * 128 + t] = float2{m, s};
    }
}

// --------------------------------------------------------- final reduce -----
// R7 structure (measured-good); packed float2 loads (one 8B load per
// plane per merge instead of two 4B loads from arrays 8 MB apart).
__global__ void reduce_kernel(const float2* __restrict__ row_ms,
                              const float2* __restrict__ col_ms,
                              const float* __restrict__ diag, float* __restrict__ out) {
    const int w = threadIdx.x >> 6, lane = threadIdx.x & 63;
    const int row = blockIdx.x * 64 + lane;
    const size_t jt0 = (size_t)w * 32;

    float2 v0 = row_ms[jt0 * N_ROWS + row];
    float m = v0.x, s = v0.y;
    for (int k = 1; k < 32; ++k) {
        float2 v = row_ms[(jt0 + k) * N_ROWS + row];
        lse_merge2(m, s, v.x, v.y);
    }
    float2 c0 = col_ms[jt0 * N_ROWS + row];
    float mc = c0.x, sc = c0.y;
    for (int k = 1; k < 32; ++k) {
        float2 v = col_ms[(jt0 + k) * N_ROWS + row];
        lse_merge2(mc, sc, v.x, v.y);
    }

    __shared__ float sm[4][64], ss[4][64], tm[4][64], ts[4][64];
    sm[w][lane] = m;  ss[w][lane] = s;
    tm[w][lane] = mc; ts[w][lane] = sc;
    __syncthreads();

    if (w == 0) {
#pragma unroll
        for (int h = 1; h < 4; ++h) lse_merge2(m, s, sm[h][lane], ss[h][lane]);
        float lse_r = m + log2f(s);
#pragma unroll
        for (int h = 1; h < 4; ++h) lse_merge2(mc, sc, tm[h][lane], ts[h][lane]);
        float lse_c = mc + log2f(sc);
        float contrib = 0.5f * LN2F * (lse_r + lse_c) - diag[row];
        for (int mask = 32; mask; mask >>= 1) contrib += __shfl_xor(contrib, mask);
        if (lane == 0) atomicAdd(out, contrib * (1.0f / N_ROWS));
    }
}

// -------------------------------------------------------------- launch ------
extern "C" void kernel_launch(void* const* d_in, const int* in_sizes, int n_in,
                              void* d_out, int out_size, void* d_ws, size_t ws_size,
                              hipStream_t stream) {
    const float* img = (const float*)d_in[0];
    const float* txt = (const float*)d_in[1];
    char* ws = (char*)d_ws;

    const size_t MB = 1024 * 1024;
    unsigned char* A8 = (unsigned char*)(ws);                   // 8 MB fp8 swizzled CF*img
    unsigned char* B8 = (unsigned char*)(ws + 8 * MB);          // 8 MB fp8 swizzled txt
    float2* row_ms = (float2*)(ws + 16 * MB);                   // 16 MB packed (m,s)
    float2* col_ms = (float2*)(ws + 32 * MB);                   // 16 MB packed (m,s)
    float* diag  = (float*)(ws + 48 * MB);                      // 64 KB
    float* out   = (float*)d_out;

    cvt_diag_kernel<<<N_ROWS / 16, 256, 0, stream>>>(img, txt, A8, B8, diag, out);
    gemm_lse_kernel<<<NB * NB, 256, 0, stream>>>(A8, B8, row_ms, col_ms);
    reduce_kernel<<<N_ROWS / 64, 256, 0, stream>>>(row_ms, col_ms, diag, out);
}

// Round 10
// 282.172 us; speedup vs baseline: 1.3269x; 1.3269x over previous
//
#include <hip/hip_runtime.h>
#include <cstdint>
#include <cstddef>
#include <cmath>

// ClipLoss fused: loss = mean_i( 0.5*(lse_row_i + lse_col_i) - diag_i )
// logits = SCALE * img @ txt^T. Stats in exp2 domain: fp8 img copy is
// pre-scaled by CF = SCALE*log2(e); lse_nat = ln2 * (m + log2(s)).
//
// A'/B' stored as e4m3 pre-swizzled [g][row][32 fp8] (g = 32-elem
// k-granule, 16 total). 16x16x128 f8f6f4 MFMA, unit E8M0 scales.
//
// History: R9 LDS dbuf / R11 256x128 tile: occupancy losses, reverted.
// R12 WIN: direct global->VGPR K-loop, no staging/barriers: gemm 196us.
// R13/R15/R16 all FAILED with the same scratch signature (WRITE_SIZE
// 69k->491k): common factor isolated by R16 = s_setprio in the unrolled
// K-loop. Mechanism: setprio partitions scheduling regions -> all 16
// loads live at once instead of interleaved with MFMAs -> spill.
// SETPRIO IS BANNED HERE. (int8v aggregates were innocent bystanders in
// R13/R15 but int4v+frag8 is the proven-good form; keeping it.)
// R14 WIN (best, 283.9us): R12 K-loop + float2-packed stats, gemm 203.
//
// R17 (this round): exact R14 gemm/cvt/memset + split reduce:
// row-LSE and col-LSE in SEPARATE blocks (grid 512 = 2 blocks/CU).
// Per-thread dependent merge chain halves (64 -> 32 latency-bound
// steps); loss decomposes exactly: row-block adds 0.5*ln2*lse_r -
// diag[i], col-block adds 0.5*ln2*lse_c.

#define N_ROWS 16384
#define DIM    512
#define NB     128
#define SCALE  14.285714285714286f
#define CF     20.609929155556625f   // SCALE * log2(e)
#define LN2F   0.6931471805599453f
#define SP     36                    // part[] row stride in floats (144 B)

typedef __attribute__((ext_vector_type(8))) int   int8v;
typedef __attribute__((ext_vector_type(4))) int   int4v;
typedef __attribute__((ext_vector_type(4))) float floatx4;

#if __has_builtin(__builtin_amdgcn_exp2f)
#define EXP2(x) __builtin_amdgcn_exp2f(x)
#else
#define EXP2(x) exp2f(x)
#endif

// ---------------------------------------------------------------- helpers ---
__device__ __forceinline__ void lse_merge2(float& m, float& s, float om, float os) {
    float nm = fmaxf(m, om);
    s = s * EXP2(m - nm) + os * EXP2(om - nm);
    m = nm;
}

// pack 4 floats -> 4 e4m3 bytes in one i32 (RNE, OCP on gfx950)
__device__ __forceinline__ int pk_fp8x4(float a, float b, float c, float d) {
    int u = __builtin_amdgcn_cvt_pk_fp8_f32(a, b, 0, false);
    u = __builtin_amdgcn_cvt_pk_fp8_f32(c, d, u, true);
    return u;
}

__device__ __forceinline__ int8v frag8(int4v lo, int4v hi) {
    return (int8v){lo[0], lo[1], lo[2], lo[3], hi[0], hi[1], hi[2], hi[3]};
}

// --------------------------------------------- cvt + swizzle + diag ---------
// Block = 256 threads = 16 rows x 16 granules. Thread (rl, g16) converts
// img/txt[row][g16*32 .. +31] to fp8 (img scaled by CF) and writes the
// 32-B granule to A'/B' at ((g16*N + row)*32); also partial diag dot.
__global__ void cvt_diag_kernel(const float* __restrict__ a, const float* __restrict__ b,
                                unsigned char* __restrict__ A8, unsigned char* __restrict__ B8,
                                float* __restrict__ diag) {
    const int t  = threadIdx.x;
    const int rl = t & 15, g16 = t >> 4;
    const int row = blockIdx.x * 16 + rl;
    const float4* ai = (const float4*)(a + (size_t)row * DIM + g16 * 32);
    const float4* bi = (const float4*)(b + (size_t)row * DIM + g16 * 32);
    float dot = 0.f;
    int wa[8], wb[8];
#pragma unroll
    for (int j = 0; j < 4; ++j) {
        float4 x0 = ai[2 * j], x1 = ai[2 * j + 1];
        float4 y0 = bi[2 * j], y1 = bi[2 * j + 1];
        dot += x0.x * y0.x + x0.y * y0.y + x0.z * y0.z + x0.w * y0.w
             + x1.x * y1.x + x1.y * y1.y + x1.z * y1.z + x1.w * y1.w;
        wa[2 * j]     = pk_fp8x4(CF * x0.x, CF * x0.y, CF * x0.z, CF * x0.w);
        wa[2 * j + 1] = pk_fp8x4(CF * x1.x, CF * x1.y, CF * x1.z, CF * x1.w);
        wb[2 * j]     = pk_fp8x4(y0.x, y0.y, y0.z, y0.w);
        wb[2 * j + 1] = pk_fp8x4(y1.x, y1.y, y1.z, y1.w);
    }
    const size_t o = ((size_t)g16 * N_ROWS + row) * 32;
    *(int4v*)(A8 + o)      = (int4v){wa[0], wa[1], wa[2], wa[3]};
    *(int4v*)(A8 + o + 16) = (int4v){wa[4], wa[5], wa[6], wa[7]};
    *(int4v*)(B8 + o)      = (int4v){wb[0], wb[1], wb[2], wb[3]};
    *(int4v*)(B8 + o + 16) = (int4v){wb[4], wb[5], wb[6], wb[7]};

    __shared__ float pd[16][17];
    pd[rl][g16] = dot;
    __syncthreads();
    if (t < 16) {
        float s = 0.f;
#pragma unroll
        for (int j = 0; j < 16; ++j) s += pd[t][j];
        diag[blockIdx.x * 16 + t] = SCALE * s;
    }
}

// --------------------------------------------------- fused GEMM + LSE -------
__global__ __launch_bounds__(256, 4)
void gemm_lse_kernel(const unsigned char* __restrict__ A8,
                     const unsigned char* __restrict__ B8,
                     float2* __restrict__ row_ms, float2* __restrict__ col_ms) {
    __shared__ __align__(16) float part[NB * SP];   // 18432 B, epilogue only

    const int t = threadIdx.x;
    const int bid = blockIdx.x;

    // XCD-aware swizzle: each XCD owns a 16-row A band (L2-resident), sweeps bc
    const int xcd   = bid & 7;
    const int local = bid >> 3;
    const int br    = xcd * 16 + (local & 15);
    const int bc    = local >> 4;

    const int lane = t & 63;
    const int w    = t >> 6;
    const int quad = lane >> 4;
    const int l15  = lane & 15;
    const int wrow = w >> 1;
    const int wcol = w & 1;

    floatx4 acc[4][4];
#pragma unroll
    for (int i = 0; i < 4; ++i)
#pragma unroll
        for (int j = 0; j < 4; ++j)
            acc[i][j] = (floatx4){0.f, 0.f, 0.f, 0.f};

    // per-lane byte offsets; granule index advances by 4 per kb step.
    // fragment (mi): 16 B at offA + mi*512 (+16 for hi half) -- 16-lane
    // groups read 512-B contiguous segments of the pre-swizzled layout.
    unsigned int offA = ((unsigned)quad * N_ROWS
                         + (unsigned)(br * 128 + wrow * 64 + l15)) * 32u;
    unsigned int offB = ((unsigned)quad * N_ROWS
                         + (unsigned)(bc * 128 + wcol * 64 + l15)) * 32u;
    const unsigned int kstep = 4u * N_ROWS * 32u;

#pragma unroll
    for (int kb = 0; kb < 4; ++kb) {
        int4v alo[4], ahi[4];
#pragma unroll
        for (int mi = 0; mi < 4; ++mi) {
            alo[mi] = *(const int4v*)(A8 + offA + mi * 512);
            ahi[mi] = *(const int4v*)(A8 + offA + mi * 512 + 16);
        }
#pragma unroll
        for (int ni = 0; ni < 4; ++ni) {
            int4v bl = *(const int4v*)(B8 + offB + ni * 512);
            int4v bh = *(const int4v*)(B8 + offB + ni * 512 + 16);
            int8v bv = frag8(bl, bh);
#pragma unroll
            for (int mi = 0; mi < 4; ++mi)
                acc[mi][ni] = __builtin_amdgcn_mfma_scale_f32_16x16x128_f8f6f4(
                    frag8(alo[mi], ahi[mi]), bv, acc[mi][ni], 0, 0, 0, 127, 0, 127);
        }
        offA += kstep;
        offB += kstep;
    }

    // ---- epilogue. C/D layout (16x16): col = lane&15, row = quad*4 + reg. ----
    // lane holds rows lrow = wrow*64+mi*16+quad*4+r, cols wcol*64+ni*16+l15.

    // phase A1: row partial max (over ni) -> part[lrow][wcol*16+l15]
#pragma unroll
    for (int mi = 0; mi < 4; ++mi)
#pragma unroll
        for (int r = 0; r < 4; ++r) {
            float pm = fmaxf(fmaxf(acc[mi][0][r], acc[mi][1][r]),
                             fmaxf(acc[mi][2][r], acc[mi][3][r]));
            int lrow = wrow * 64 + mi * 16 + quad * 4 + r;
            part[lrow * SP + wcol * 16 + l15] = pm;
        }

    // phase A2: col stats (shfl over quads) -> part[cl][32..35]
#pragma unroll
    for (int ni = 0; ni < 4; ++ni) {
        float m = acc[0][ni][0];
#pragma unroll
        for (int mi = 0; mi < 4; ++mi)
#pragma unroll
            for (int r = 0; r < 4; ++r)
                m = fmaxf(m, acc[mi][ni][r]);
        m = fmaxf(m, __shfl_xor(m, 16));
        m = fmaxf(m, __shfl_xor(m, 32));
        float s = 0.f;
#pragma unroll
        for (int mi = 0; mi < 4; ++mi)
#pragma unroll
            for (int r = 0; r < 4; ++r)
                s += EXP2(acc[mi][ni][r] - m);
        s += __shfl_xor(s, 16);
        s += __shfl_xor(s, 32);
        if (quad == 0) {
            int cl = wcol * 64 + ni * 16 + l15;
            part[cl * SP + 32 + wrow] = m;   // 32,33
            part[cl * SP + 34 + wrow] = s;   // 34,35
        }
    }
    __syncthreads();

    if (t < 128) {
        // finish cols: merge wrow halves, store packed (m,s)
        float m = part[t * SP + 32], s = part[t * SP + 34];
        lse_merge2(m, s, part[t * SP + 33], part[t * SP + 35]);
        col_ms[(size_t)br * N_ROWS + bc * 128 + t] = float2{m, s};
        // row max over 32 partials (8 x float4, stride 144 B)
        const float4* p4 = (const float4*)&part[t * SP];
        float4 v = p4[0];
#pragma unroll
        for (int j = 1; j < 8; ++j) {
            float4 u = p4[j];
            v.x = fmaxf(v.x, u.x); v.y = fmaxf(v.y, u.y);
            v.z = fmaxf(v.z, u.z); v.w = fmaxf(v.w, u.w);
        }
        part[t * SP + 32] = fmaxf(fmaxf(v.x, v.y), fmaxf(v.z, v.w));
    }
    __syncthreads();

    // phase B: row partial sums with broadcast max
#pragma unroll
    for (int mi = 0; mi < 4; ++mi)
#pragma unroll
        for (int r = 0; r < 4; ++r) {
            int lrow = wrow * 64 + mi * 16 + quad * 4 + r;
            float m = part[lrow * SP + 32];
            float s = EXP2(acc[mi][0][r] - m) + EXP2(acc[mi][1][r] - m)
                    + EXP2(acc[mi][2][r] - m) + EXP2(acc[mi][3][r] - m);
            part[lrow * SP + wcol * 16 + l15] = s;
        }
    __syncthreads();

    if (t < 128) {
        const float4* p4 = (const float4*)&part[t * SP];
        float4 v = p4[0];
#pragma unroll
        for (int j = 1; j < 8; ++j) {
            float4 u = p4[j];
            v.x += u.x; v.y += u.y; v.z += u.z; v.w += u.w;
        }
        float s = (v.x + v.y) + (v.z + v.w);
        float m = part[t * SP + 32];
        row_ms[(size_t)bc * N_ROWS + br * 128 + t] = float2{m, s};
    }
}

// --------------------------------------------------------- final reduce -----
// R17: split grid -- blocks [0,256) do row-LSE, [256,512) do col-LSE.
// Same per-block structure as the R7-measured-good reduce, but each
// thread's dependent merge chain is 32 steps instead of 64, and
// blocks/CU doubles. Loss decomposes exactly across the two halves.
__global__ void reduce_kernel(const float2* __restrict__ row_ms,
                              const float2* __restrict__ col_ms,
                              const float* __restrict__ diag, float* __restrict__ out) {
    const int w = threadIdx.x >> 6, lane = threadIdx.x & 63;
    const bool isCol = blockIdx.x >= (N_ROWS / 64);
    const int blk = isCol ? (int)blockIdx.x - N_ROWS / 64 : (int)blockIdx.x;
    const int row = blk * 64 + lane;
    const float2* __restrict__ src = isCol ? col_ms : row_ms;
    const size_t jt0 = (size_t)w * 32;

    float2 v0 = src[jt0 * N_ROWS + row];
    float m = v0.x, s = v0.y;
    for (int k = 1; k < 32; ++k) {
        float2 v = src[(jt0 + k) * N_ROWS + row];
        lse_merge2(m, s, v.x, v.y);
    }

    __shared__ float sm[4][64], ss[4][64];
    sm[w][lane] = m;  ss[w][lane] = s;
    __syncthreads();

    if (w == 0) {
#pragma unroll
        for (int h = 1; h < 4; ++h) lse_merge2(m, s, sm[h][lane], ss[h][lane]);
        float lse = m + log2f(s);
        float contrib = 0.5f * LN2F * lse - (isCol ? 0.f : diag[row]);
        for (int mask = 32; mask; mask >>= 1) contrib += __shfl_xor(contrib, mask);
        if (lane == 0) atomicAdd(out, contrib * (1.0f / N_ROWS));
    }
}

// -------------------------------------------------------------- launch ------
extern "C" void kernel_launch(void* const* d_in, const int* in_sizes, int n_in,
                              void* d_out, int out_size, void* d_ws, size_t ws_size,
                              hipStream_t stream) {
    const float* img = (const float*)d_in[0];
    const float* txt = (const float*)d_in[1];
    char* ws = (char*)d_ws;

    const size_t MB = 1024 * 1024;
    unsigned char* A8 = (unsigned char*)(ws);                   // 8 MB fp8 swizzled CF*img
    unsigned char* B8 = (unsigned char*)(ws + 8 * MB);          // 8 MB fp8 swizzled txt
    float2* row_ms = (float2*)(ws + 16 * MB);                   // 16 MB packed (m,s)
    float2* col_ms = (float2*)(ws + 32 * MB);                   // 16 MB packed (m,s)
    float* diag  = (float*)(ws + 48 * MB);                      // 64 KB
    float* out   = (float*)d_out;

    hipMemsetAsync(d_out, 0, sizeof(float), stream);
    cvt_diag_kernel<<<N_ROWS / 16, 256, 0, stream>>>(img, txt, A8, B8, diag);
    gemm_lse_kernel<<<NB * NB, 256, 0, stream>>>(A8, B8, row_ms, col_ms);
    reduce_kernel<<<2 * (N_ROWS / 64), 256, 0, stream>>>(row_ms, col_ms, diag, out);
}